// Round 11
// baseline (288.613 us; speedup 1.0000x reference)
//
#include <hip/hip_runtime.h>

typedef unsigned short u16;
typedef __attribute__((ext_vector_type(8))) short s16x8;
typedef __attribute__((ext_vector_type(4))) short s16x4;
typedef __attribute__((ext_vector_type(8))) unsigned short u16x8;
typedef __attribute__((ext_vector_type(4))) unsigned short u16x4;
typedef __attribute__((ext_vector_type(4))) float f32x4;

#define B_ 2
#define S_ 2048
#define HID_ 2048
#define NH_ 32
#define NKV_ 8
#define HD_ 64
#define M_ (B_ * S_)          // 4096
#define NQKV_ 3072            // 2048 q + 512 k + 512 v

__device__ __forceinline__ u16 bf16rne(float f) {
    union { float f; unsigned u; } x; x.f = f;
    unsigned u = x.u;
    u += 0x7fffu + ((u >> 16) & 1u);
    return (u16)(u >> 16);
}
__device__ __forceinline__ float bf16tof(u16 h) {
    union { unsigned u; float f; } x; x.u = ((unsigned)h) << 16;
    return x.f;
}
__device__ __forceinline__ f32x4 vmax4(f32x4 a, f32x4 b) {
    f32x4 r;
    r[0] = fmaxf(a[0], b[0]); r[1] = fmaxf(a[1], b[1]);
    r[2] = fmaxf(a[2], b[2]); r[3] = fmaxf(a[3], b[3]);
    return r;
}
__device__ __forceinline__ f32x4 mfma16x16x16_bf16(s16x4 a, s16x4 b, f32x4 c) {
#if __has_builtin(__builtin_amdgcn_mfma_f32_16x16x16bf16_1k)
    return __builtin_amdgcn_mfma_f32_16x16x16bf16_1k(a, b, c, 0, 0, 0);
#else
    f32x4 d = c;
    asm volatile("v_mfma_f32_16x16x16_bf16 %0, %1, %2, %0" : "+v"(d) : "v"(a), "v"(b));
    return d;
#endif
}

// async global->LDS, 16B per lane; LDS dest = wave-uniform base + lane*16
__device__ __forceinline__ void gload16(const void* g, void* l) {
    __builtin_amdgcn_global_load_lds(
        (const __attribute__((address_space(1))) unsigned int*)g,
        (__attribute__((address_space(3))) unsigned int*)l, 16, 0, 0);
}

// ---------------- fp32 -> bf16 convert (x) ----------------
__global__ __launch_bounds__(256) void convert_x_kernel(const float* __restrict__ src,
                                                        u16* __restrict__ dst, int n4) {
    int i = blockIdx.x * 256 + threadIdx.x;
    if (i >= n4) return;
    f32x4 v = *(const f32x4*)(src + (size_t)i * 4);
    u16x4 o;
    o[0] = bf16rne(v[0]); o[1] = bf16rne(v[1]); o[2] = bf16rne(v[2]); o[3] = bf16rne(v[3]);
    *(u16x4*)(dst + (size_t)i * 4) = o;
}

// ---------------- pack qkv bias (fp32) ----------------
__global__ void pack_bias_kernel(const float* bq, const float* bk, const float* bv,
                                 float* __restrict__ dst) {
    int i = blockIdx.x * 256 + threadIdx.x;
    if (i >= NQKV_) return;
    float v;
    if (i < 2048) v = bq[i];
    else if (i < 2560) v = bk[i - 2048];
    else v = bv[i - 2560];
    dst[i] = v;
}

// ---------------- transpose+convert W: src [2048][N] f32 -> dst[n][k] bf16 (dst row stride 2048)
__global__ __launch_bounds__(256) void transpose_w_kernel(const float* __restrict__ src, int N,
                                                          u16* __restrict__ dst) {
    __shared__ float tile[32][33];
    int n0 = blockIdx.x * 32;
    int k0 = blockIdx.y * 32;
    int tx = threadIdx.x;   // 0..31
    int ty = threadIdx.y;   // 0..7
    for (int i = 0; i < 32; i += 8)
        tile[ty + i][tx] = src[(size_t)(k0 + ty + i) * N + n0 + tx];
    __syncthreads();
    for (int i = 0; i < 32; i += 8)
        dst[(size_t)(n0 + ty + i) * 2048 + k0 + tx] = bf16rne(tile[tx][ty + i]);
}

// ---------------- transpose V slice out of qkv: vT[bh][d][s] ----------------
__global__ __launch_bounds__(256) void transpose_v_kernel(const u16* __restrict__ qkv,
                                                          u16* __restrict__ vT) {
    __shared__ u16 tile[32][33];
    int bh = blockIdx.z;              // b*8+kv
    int b = bh >> 3, kv = bh & 7;
    const u16* src = qkv + (size_t)(b * S_) * NQKV_ + 2560 + kv * 64;
    u16* dst = vT + (size_t)bh * 64 * S_;
    int s0 = blockIdx.x * 32;
    int d0 = blockIdx.y * 32;
    int tx = threadIdx.x, ty = threadIdx.y;
    for (int i = 0; i < 32; i += 8)
        tile[ty + i][tx] = src[(size_t)(s0 + ty + i) * NQKV_ + d0 + tx];
    __syncthreads();
    for (int i = 0; i < 32; i += 8)
        dst[(size_t)(d0 + ty + i) * S_ + s0 + tx] = tile[tx][ty + i];
}

// ---------------- bf16 GEMM (m97 structure + T1 XCD swizzle) ----------------
// C[M][N] = A[M][K]*Bt[N][K]^T + bias; 128x128 tile, BK=64, 4 waves 2x2.
template <bool OUT_BF16>
__global__ __launch_bounds__(256) void gemm_bt_kernel(const u16* __restrict__ A,
                                                      const u16* __restrict__ Bt,
                                                      const float* __restrict__ bias,
                                                      void* __restrict__ Cout,
                                                      int M, int N, int K) {
    __shared__ u16 As[128][64];
    __shared__ u16 Bs[128][64];
    // T1: XCD-aware block swizzle (requires nwg % 8 == 0 -- true for 768 and 512)
    int nwg = (int)(gridDim.x * gridDim.y);
    int bid = (int)(blockIdx.y * gridDim.x + blockIdx.x);
    int swz = (bid & 7) * (nwg >> 3) + (bid >> 3);
    int bn = (swz % (int)gridDim.x) * 128;
    int bm = (swz / (int)gridDim.x) * 128;
    int tid = threadIdx.x;
    int lane = tid & 63, wid = tid >> 6;
    int wr = wid >> 1, wc = wid & 1;
    int lr = lane & 15, lg = lane >> 4;
    f32x4 acc[4][4] = {};

    int srow_l = lane >> 3;                 // 0..7
    int schunk = (lane & 7) ^ srow_l;       // source chunk for linear LDS dest (XOR swizzle)
    int scol = schunk * 8;                  // element offset in K

    for (int k0 = 0; k0 < K; k0 += 64) {
        __syncthreads();   // previous compute done before overwrite
#pragma unroll
        for (int c = 0; c < 4; c++) {
            int row = c * 32 + wid * 8;
            gload16(A + (size_t)(bm + row + srow_l) * K + k0 + scol, &As[row][0]);
            gload16(Bt + (size_t)(bn + row + srow_l) * K + k0 + scol, &Bs[row][0]);
        }
        asm volatile("s_waitcnt vmcnt(0)" ::: "memory");
        __syncthreads();   // all waves' loads landed
#pragma unroll
        for (int kk = 0; kk < 2; kk++) {
            s16x8 a[4], b[4];
#pragma unroll
            for (int mi = 0; mi < 4; mi++) {
                int row = wr * 64 + mi * 16 + lr;
                int cc = ((kk << 2) + lg) ^ (lr & 7);
                a[mi] = *(const s16x8*)&As[row][cc << 3];
            }
#pragma unroll
            for (int ni = 0; ni < 4; ni++) {
                int row = wc * 64 + ni * 16 + lr;
                int cc = ((kk << 2) + lg) ^ (lr & 7);
                b[ni] = *(const s16x8*)&Bs[row][cc << 3];
            }
#pragma unroll
            for (int mi = 0; mi < 4; mi++)
#pragma unroll
                for (int ni = 0; ni < 4; ni++)
                    acc[mi][ni] = __builtin_amdgcn_mfma_f32_16x16x32_bf16(a[mi], b[ni], acc[mi][ni], 0, 0, 0);
        }
    }

#pragma unroll
    for (int mi = 0; mi < 4; mi++)
#pragma unroll
        for (int ni = 0; ni < 4; ni++) {
            int col = bn + wc * 64 + ni * 16 + lr;
            float bsv = bias ? bias[col] : 0.0f;
#pragma unroll
            for (int r = 0; r < 4; r++) {
                int row = bm + wr * 64 + mi * 16 + lg * 4 + r;
                float v = acc[mi][ni][r] + bsv;
                if (OUT_BF16)
                    ((u16*)Cout)[(size_t)row * N + col] = bf16rne(v);
                else
                    ((float*)Cout)[(size_t)row * N + col] = v;
            }
        }
}

// ---------------- flash attention v10: 1024 blocks (full occupancy), shared K/V staging ----
// 8 waves / 4 q-heads share staged K/V; one 32-row q-tile per block; reverse dispatch.
// Q prescaled by 0.125*log2(e); softmax exp2-domain, always-rescale (P<=1), RNE pack.
// Swapped QK^T: lane (lr,lg) reg r = S[kv=16t4+4lg+r][q=lr].
// Transposed PV: O^T = V^T*P (16x16x16); alpha/l lane-local; contiguous 8B epilogue stores.
__global__ __launch_bounds__(512) void attn_kernel(const u16* __restrict__ qkv,
                                                   const u16* __restrict__ vT,
                                                   u16* __restrict__ attn_out) {
    int qt = 63 - (int)blockIdx.x;   // 32-row q-tile; heavy (large-nt) blocks dispatch first
    int bkv = blockIdx.y;            // 0..15
    int b = bkv >> 3, kvh = bkv & 7;
    int tid = threadIdx.x;
    int lane = tid & 63, wid = tid >> 6;   // 8 waves
    int lr = lane & 15, lg = lane >> 4;
    int h = kvh * 4 + (wid >> 1);    // q head: 2 waves per head
    int sub = wid & 1;               // 16-row subtile within the 32-row q-tile
    int qrow0 = qt * 32 + sub * 16;  // this wave's first q row
    int nt = qt / 2 + 1;             // kv tiles of 64 covering causal extent

    __shared__ u16 Ks[2][64][72];    // [buf][kv][d] padded (144B stride)
    __shared__ u16 Vs[2][64][72];    // [buf][d][kv] padded

    const u16* Kbase = qkv + (size_t)(b * S_) * NQKV_ + 2048 + kvh * 64;  // + s*NQKV_
    const u16* Vbase = vT + (size_t)(b * 8 + kvh) * 64 * S_;              // + d*S_

    int srow = tid >> 3;             // 0..63 (one staging pass, 512 threads)
    int scol = (tid & 7) * 8;

    // Q as B-fragment: lane holds Q[q=lr][d = db*32 + lg*8 + j], prescaled
    s16x8 qf[2];
    {
        const u16* qr = qkv + (size_t)(b * S_ + qrow0 + lr) * NQKV_ + h * 64;
#pragma unroll
        for (int db = 0; db < 2; db++) {
            u16x8 u = *(const u16x8*)(qr + db * 32 + lg * 8);
            s16x8 s;
#pragma unroll
            for (int j = 0; j < 8; j++) s[j] = (short)bf16rne(bf16tof(u[j]) * 0.18033688f);
            qf[db] = s;
        }
    }

    f32x4 O[4] = {};                 // O^T: O[dt] reg r = O[q=lr][d = 16dt + 4lg + r]
    float m_i = -1e30f, l_i = 0.0f;  // for q-row (qrow0 + lr)

    // prologue: stage kv tile 0 into buf 0
    {
        u16x8 k0v = *(const u16x8*)(Kbase + (size_t)srow * NQKV_ + scol);
        u16x8 v0v = *(const u16x8*)(Vbase + (size_t)srow * S_ + scol);
        *(u16x8*)&Ks[0][srow][scol] = k0v;
        *(u16x8*)&Vs[0][srow][scol] = v0v;
    }
    __syncthreads();

    int cb = 0;
    for (int t = 0; t < nt; t++) {
        int kv0 = t * 64;
        bool notlast = (t + 1 < nt);
        // T14: issue next tile's global loads early (hide HBM/L2 under compute)
        u16x8 kn, vn;
        if (notlast) {
            kn = *(const u16x8*)(Kbase + (size_t)(kv0 + 64 + srow) * NQKV_ + scol);
            vn = *(const u16x8*)(Vbase + (size_t)srow * S_ + kv0 + 64 + scol);
        }

        // swapped QK^T: Sc[t4][r] = S[kv0+16t4+4lg+r][qrow0+lr]
        f32x4 Sc[4] = {};
        __builtin_amdgcn_s_setprio(1);
#pragma unroll
        for (int t4 = 0; t4 < 4; t4++) {
#pragma unroll
            for (int db = 0; db < 2; db++) {
                s16x8 kf = *(const s16x8*)&Ks[cb][t4 * 16 + lr][db * 32 + lg * 8];
                Sc[t4] = __builtin_amdgcn_mfma_f32_16x16x32_bf16(kf, qf[db], Sc[t4], 0, 0, 0);
            }
        }
        __builtin_amdgcn_s_setprio(0);
        // causal mask: only last tile is partial (block-uniform branch)
        if (t == nt - 1) {
            int qr = qrow0 + lr;
#pragma unroll
            for (int t4 = 0; t4 < 4; t4++)
#pragma unroll
                for (int r = 0; r < 4; r++) {
                    int kvi = kv0 + t4 * 16 + lg * 4 + r;
                    Sc[t4][r] = (kvi <= qr) ? Sc[t4][r] : -1e30f;
                }
        }
        // lane-local softmax for q-row (qrow0+lr); row spread over lanes {lr,+16,+32,+48}
        f32x4 mm = vmax4(vmax4(Sc[0], Sc[1]), vmax4(Sc[2], Sc[3]));
        float mx = fmaxf(fmaxf(mm[0], mm[1]), fmaxf(mm[2], mm[3]));
        mx = fmaxf(mx, __shfl_xor(mx, 16));
        mx = fmaxf(mx, __shfl_xor(mx, 32));
        float newm = fmaxf(m_i, mx);
        float alpha = exp2f(m_i - newm);
        m_i = newm;
        f32x4 p4[4];
#pragma unroll
        for (int t4 = 0; t4 < 4; t4++)
#pragma unroll
            for (int r = 0; r < 4; r++)
                p4[t4][r] = exp2f(Sc[t4][r] - newm);
        f32x4 ss = (p4[0] + p4[1]) + (p4[2] + p4[3]);
        float rs = (ss[0] + ss[1]) + (ss[2] + ss[3]);
        rs += __shfl_xor(rs, 16);
        rs += __shfl_xor(rs, 32);
        l_i = l_i * alpha + rs;
        // O rescale: alpha belongs to q=lr == this lane's O rows (lane-local)
#pragma unroll
        for (int dt = 0; dt < 4; dt++)
#pragma unroll
            for (int r = 0; r < 4; r++) O[dt][r] *= alpha;
        // pack P to bf16 B-fragments in-register (RNE; cvt_pk truncates -> bias, rounds 6/8)
        s16x4 pa[4];
#pragma unroll
        for (int t4 = 0; t4 < 4; t4++) {
            u16x4 w;
#pragma unroll
            for (int r = 0; r < 4; r++) w[r] = bf16rne(p4[t4][r]);
            union { u16x4 u; s16x4 s; } uu; uu.u = w;
            pa[t4] = uu.s;
        }
        // PV transposed: O^T += V^T * P; A-frag = Vs rows (8B LDS reads), B-frag = pa
        __builtin_amdgcn_s_setprio(1);
#pragma unroll
        for (int t4 = 0; t4 < 4; t4++) {
#pragma unroll
            for (int dt = 0; dt < 4; dt++) {
                s16x4 va = *(const s16x4*)&Vs[cb][dt * 16 + lr][t4 * 16 + lg * 4];
                O[dt] = mfma16x16x16_bf16(va, pa[t4], O[dt]);
            }
        }
        __builtin_amdgcn_s_setprio(0);
        // write staged regs to the other buffer (nobody reads it this iter)
        if (notlast) {
            *(u16x8*)&Ks[cb ^ 1][srow][scol] = kn;
            *(u16x8*)&Vs[cb ^ 1][srow][scol] = vn;
        }
        __syncthreads();             // single barrier: staging visible + reads done
        cb ^= 1;
    }

    // epilogue: lane-local 1/l; lane writes q-row (qrow0+lr), 4 contiguous d per dt
    float il = 1.0f / l_i;
    u16* orow = attn_out + (size_t)(b * S_ + qrow0 + lr) * HID_ + h * 64 + lg * 4;
#pragma unroll
    for (int dt = 0; dt < 4; dt++) {
        u16x4 w;
#pragma unroll
        for (int r = 0; r < 4; r++) w[r] = bf16rne(O[dt][r] * il);
        *(u16x4*)(orow + dt * 16) = w;
    }
}

extern "C" void kernel_launch(void* const* d_in, const int* in_sizes, int n_in,
                              void* d_out, int out_size, void* d_ws, size_t ws_size,
                              hipStream_t stream) {
    const float* x  = (const float*)d_in[0];
    // d_in[1] = mask (causal, implemented structurally)
    const float* Wq = (const float*)d_in[2];
    const float* bq = (const float*)d_in[3];
    const float* Wk = (const float*)d_in[4];
    const float* bk = (const float*)d_in[5];
    const float* Wv = (const float*)d_in[6];
    const float* bv = (const float*)d_in[7];
    const float* Wo = (const float*)d_in[8];
    const float* bo = (const float*)d_in[9];
    float* out = (float*)d_out;

    char* ws = (char*)d_ws;
    u16* xb     = (u16*)(ws);                              // 16.78 MB
    u16* wqkvT  = (u16*)(ws + 16777216);                   // 12.58 MB
    u16* woT    = (u16*)(ws + 29360128);                   // 8.39 MB
    u16* qkv    = (u16*)(ws + 37748736);                   // 25.17 MB
    u16* vT     = (u16*)(ws + 62914560);                   // 4.19 MB
    u16* attnO  = (u16*)(ws + 67108864);                   // 16.78 MB
    float* biasQ = (float*)(ws + 83886080);                // 12 KB

    // 1. convert x to bf16
    {
        int n4 = (M_ * HID_) / 4;  // 2097152
        convert_x_kernel<<<(n4 + 255) / 256, 256, 0, stream>>>(x, xb, n4);
    }
    // 2. pack qkv bias
    pack_bias_kernel<<<(NQKV_ + 255) / 256, 256, 0, stream>>>(bq, bk, bv, biasQ);
    // 3. transpose weights
    {
        dim3 blk(32, 8);
        transpose_w_kernel<<<dim3(64, 64), blk, 0, stream>>>(Wq, 2048, wqkvT);
        transpose_w_kernel<<<dim3(16, 64), blk, 0, stream>>>(Wk, 512, wqkvT + (size_t)2048 * 2048);
        transpose_w_kernel<<<dim3(16, 64), blk, 0, stream>>>(Wv, 512, wqkvT + (size_t)2560 * 2048);
        transpose_w_kernel<<<dim3(64, 64), blk, 0, stream>>>(Wo, 2048, woT);
    }
    // 4. QKV GEMM: [4096,3072] = xb @ wqkvT^T + biasQ  (bf16 out)
    gemm_bt_kernel<true><<<dim3(NQKV_ / 128, M_ / 128), 256, 0, stream>>>(
        xb, wqkvT, biasQ, qkv, M_, NQKV_, HID_);
    // 5. transpose V
    transpose_v_kernel<<<dim3(64, 2, 16), dim3(32, 8), 0, stream>>>(qkv, vT);
    // 6. attention: 1024 blocks (full wave capacity), 8 waves / 4 heads share staged K/V
    attn_kernel<<<dim3(64, B_ * NKV_), 512, 0, stream>>>(qkv, vT, attnO);
    // 7. output GEMM: [4096,2048] = attnO @ woT^T + bo  (fp32 out)
    gemm_bt_kernel<false><<<dim3(HID_ / 128, M_ / 128), 256, 0, stream>>>(
        attnO, woT, bo, out, M_, HID_, HID_);
}

// Round 12
// 228.128 us; speedup vs baseline: 1.2651x; 1.2651x over previous
//
#include <hip/hip_runtime.h>

typedef unsigned short u16;
typedef __attribute__((ext_vector_type(8))) short s16x8;
typedef __attribute__((ext_vector_type(4))) short s16x4;
typedef __attribute__((ext_vector_type(8))) unsigned short u16x8;
typedef __attribute__((ext_vector_type(4))) unsigned short u16x4;
typedef __attribute__((ext_vector_type(4))) float f32x4;

#define B_ 2
#define S_ 2048
#define HID_ 2048
#define NH_ 32
#define NKV_ 8
#define HD_ 64
#define M_ (B_ * S_)          // 4096
#define NQKV_ 3072            // 2048 q + 512 k + 512 v

__device__ __forceinline__ u16 bf16rne(float f) {
    union { float f; unsigned u; } x; x.f = f;
    unsigned u = x.u;
    u += 0x7fffu + ((u >> 16) & 1u);
    return (u16)(u >> 16);
}
__device__ __forceinline__ float bf16tof(u16 h) {
    union { unsigned u; float f; } x; x.u = ((unsigned)h) << 16;
    return x.f;
}
__device__ __forceinline__ f32x4 vmax4(f32x4 a, f32x4 b) {
    f32x4 r;
    r[0] = fmaxf(a[0], b[0]); r[1] = fmaxf(a[1], b[1]);
    r[2] = fmaxf(a[2], b[2]); r[3] = fmaxf(a[3], b[3]);
    return r;
}
__device__ __forceinline__ f32x4 mfma16x16x16_bf16(s16x4 a, s16x4 b, f32x4 c) {
#if __has_builtin(__builtin_amdgcn_mfma_f32_16x16x16bf16_1k)
    return __builtin_amdgcn_mfma_f32_16x16x16bf16_1k(a, b, c, 0, 0, 0);
#else
    f32x4 d = c;
    asm volatile("v_mfma_f32_16x16x16_bf16 %0, %1, %2, %0" : "+v"(d) : "v"(a), "v"(b));
    return d;
#endif
}

// async global->LDS, 16B per lane; LDS dest = wave-uniform base + lane*16
__device__ __forceinline__ void gload16(const void* g, void* l) {
    __builtin_amdgcn_global_load_lds(
        (const __attribute__((address_space(1))) unsigned int*)g,
        (__attribute__((address_space(3))) unsigned int*)l, 16, 0, 0);
}

// ---------------- fp32 -> bf16 convert (x) ----------------
__global__ __launch_bounds__(256) void convert_x_kernel(const float* __restrict__ src,
                                                        u16* __restrict__ dst, int n4) {
    int i = blockIdx.x * 256 + threadIdx.x;
    if (i >= n4) return;
    f32x4 v = *(const f32x4*)(src + (size_t)i * 4);
    u16x4 o;
    o[0] = bf16rne(v[0]); o[1] = bf16rne(v[1]); o[2] = bf16rne(v[2]); o[3] = bf16rne(v[3]);
    *(u16x4*)(dst + (size_t)i * 4) = o;
}

// ---------------- pack qkv bias (fp32) ----------------
__global__ void pack_bias_kernel(const float* bq, const float* bk, const float* bv,
                                 float* __restrict__ dst) {
    int i = blockIdx.x * 256 + threadIdx.x;
    if (i >= NQKV_) return;
    float v;
    if (i < 2048) v = bq[i];
    else if (i < 2560) v = bk[i - 2048];
    else v = bv[i - 2560];
    dst[i] = v;
}

// ---------------- transpose+convert W: src [2048][N] f32 -> dst[n][k] bf16 (dst row stride 2048)
__global__ __launch_bounds__(256) void transpose_w_kernel(const float* __restrict__ src, int N,
                                                          u16* __restrict__ dst) {
    __shared__ float tile[32][33];
    int n0 = blockIdx.x * 32;
    int k0 = blockIdx.y * 32;
    int tx = threadIdx.x;   // 0..31
    int ty = threadIdx.y;   // 0..7
    for (int i = 0; i < 32; i += 8)
        tile[ty + i][tx] = src[(size_t)(k0 + ty + i) * N + n0 + tx];
    __syncthreads();
    for (int i = 0; i < 32; i += 8)
        dst[(size_t)(n0 + ty + i) * 2048 + k0 + tx] = bf16rne(tile[tx][ty + i]);
}

// ---------------- transpose V slice out of qkv: vT[bh][d][s] ----------------
__global__ __launch_bounds__(256) void transpose_v_kernel(const u16* __restrict__ qkv,
                                                          u16* __restrict__ vT) {
    __shared__ u16 tile[32][33];
    int bh = blockIdx.z;              // b*8+kv
    int b = bh >> 3, kv = bh & 7;
    const u16* src = qkv + (size_t)(b * S_) * NQKV_ + 2560 + kv * 64;
    u16* dst = vT + (size_t)bh * 64 * S_;
    int s0 = blockIdx.x * 32;
    int d0 = blockIdx.y * 32;
    int tx = threadIdx.x, ty = threadIdx.y;
    for (int i = 0; i < 32; i += 8)
        tile[ty + i][tx] = src[(size_t)(s0 + ty + i) * NQKV_ + d0 + tx];
    __syncthreads();
    for (int i = 0; i < 32; i += 8)
        dst[(size_t)(d0 + ty + i) * S_ + s0 + tx] = tile[tx][ty + i];
}

// ---------------- bf16 GEMM (m97 structure + T1 XCD swizzle) ----------------
// C[M][N] = A[M][K]*Bt[N][K]^T + bias; 128x128 tile, BK=64, 4 waves 2x2.
template <bool OUT_BF16>
__global__ __launch_bounds__(256) void gemm_bt_kernel(const u16* __restrict__ A,
                                                      const u16* __restrict__ Bt,
                                                      const float* __restrict__ bias,
                                                      void* __restrict__ Cout,
                                                      int M, int N, int K) {
    __shared__ u16 As[128][64];
    __shared__ u16 Bs[128][64];
    // T1: XCD-aware block swizzle (requires nwg % 8 == 0 -- true for 768 and 512)
    int nwg = (int)(gridDim.x * gridDim.y);
    int bid = (int)(blockIdx.y * gridDim.x + blockIdx.x);
    int swz = (bid & 7) * (nwg >> 3) + (bid >> 3);
    int bn = (swz % (int)gridDim.x) * 128;
    int bm = (swz / (int)gridDim.x) * 128;
    int tid = threadIdx.x;
    int lane = tid & 63, wid = tid >> 6;
    int wr = wid >> 1, wc = wid & 1;
    int lr = lane & 15, lg = lane >> 4;
    f32x4 acc[4][4] = {};

    int srow_l = lane >> 3;                 // 0..7
    int schunk = (lane & 7) ^ srow_l;       // source chunk for linear LDS dest (XOR swizzle)
    int scol = schunk * 8;                  // element offset in K

    for (int k0 = 0; k0 < K; k0 += 64) {
        __syncthreads();   // previous compute done before overwrite
#pragma unroll
        for (int c = 0; c < 4; c++) {
            int row = c * 32 + wid * 8;
            gload16(A + (size_t)(bm + row + srow_l) * K + k0 + scol, &As[row][0]);
            gload16(Bt + (size_t)(bn + row + srow_l) * K + k0 + scol, &Bs[row][0]);
        }
        asm volatile("s_waitcnt vmcnt(0)" ::: "memory");
        __syncthreads();   // all waves' loads landed
#pragma unroll
        for (int kk = 0; kk < 2; kk++) {
            s16x8 a[4], b[4];
#pragma unroll
            for (int mi = 0; mi < 4; mi++) {
                int row = wr * 64 + mi * 16 + lr;
                int cc = ((kk << 2) + lg) ^ (lr & 7);
                a[mi] = *(const s16x8*)&As[row][cc << 3];
            }
#pragma unroll
            for (int ni = 0; ni < 4; ni++) {
                int row = wc * 64 + ni * 16 + lr;
                int cc = ((kk << 2) + lg) ^ (lr & 7);
                b[ni] = *(const s16x8*)&Bs[row][cc << 3];
            }
#pragma unroll
            for (int mi = 0; mi < 4; mi++)
#pragma unroll
                for (int ni = 0; ni < 4; ni++)
                    acc[mi][ni] = __builtin_amdgcn_mfma_f32_16x16x32_bf16(a[mi], b[ni], acc[mi][ni], 0, 0, 0);
        }
    }

#pragma unroll
    for (int mi = 0; mi < 4; mi++)
#pragma unroll
        for (int ni = 0; ni < 4; ni++) {
            int col = bn + wc * 64 + ni * 16 + lr;
            float bsv = bias ? bias[col] : 0.0f;
#pragma unroll
            for (int r = 0; r < 4; r++) {
                int row = bm + wr * 64 + mi * 16 + lg * 4 + r;
                float v = acc[mi][ni][r] + bsv;
                if (OUT_BF16)
                    ((u16*)Cout)[(size_t)row * N + col] = bf16rne(v);
                else
                    ((float*)Cout)[(size_t)row * N + col] = v;
            }
        }
}

// ---------------- flash attention (r10 config): 8 waves / 4 q-heads share staged K/V; ----------
// paired causal q-tiles {bx, 63-bx} -> every block does ~33-34 kv-tile visits (zero tail).
// Q prescaled by 0.125*log2(e); softmax exp2-domain, always-rescale (P<=1), RNE pack.
// Swapped QK^T: lane (lr,lg) reg r = S[kv=16t4+4lg+r][q=lr].
// Transposed PV: O^T = V^T*P (16x16x16); alpha/l lane-local; contiguous 8B epilogue stores.
__global__ __launch_bounds__(512) void attn_kernel(const u16* __restrict__ qkv,
                                                   const u16* __restrict__ vT,
                                                   u16* __restrict__ attn_out) {
    int bx = blockIdx.x;             // 0..31
    int bkv = blockIdx.y;            // 0..15
    int b = bkv >> 3, kvh = bkv & 7;
    int tid = threadIdx.x;
    int lane = tid & 63, wid = tid >> 6;   // 8 waves
    int lr = lane & 15, lg = lane >> 4;
    int h = kvh * 4 + (wid >> 1);    // q head: 2 waves per head
    int sub = wid & 1;               // 16-row subtile within the 32-row q-tile

    __shared__ u16 Ks[2][64][72];    // [buf][kv][d] padded (144B stride)
    __shared__ u16 Vs[2][64][72];    // [buf][d][kv] padded

    const u16* Kbase = qkv + (size_t)(b * S_) * NQKV_ + 2048 + kvh * 64;  // + s*NQKV_
    const u16* Vbase = vT + (size_t)(b * 8 + kvh) * 64 * S_;              // + d*S_

    int srow = tid >> 3;             // 0..63 (one staging pass, 512 threads)
    int scol = (tid & 7) * 8;

#pragma unroll 1
    for (int phase = 0; phase < 2; phase++) {
        int qt = phase ? (63 - bx) : bx;   // 32-row q-tile index
        int qrow0 = qt * 32 + sub * 16;    // this wave's first q row
        int nt = qt / 2 + 1;               // kv tiles of 64 covering causal extent

        // Q as B-fragment: lane holds Q[q=lr][d = db*32 + lg*8 + j], prescaled
        s16x8 qf[2];
        {
            const u16* qr = qkv + (size_t)(b * S_ + qrow0 + lr) * NQKV_ + h * 64;
#pragma unroll
            for (int db = 0; db < 2; db++) {
                u16x8 u = *(const u16x8*)(qr + db * 32 + lg * 8);
                s16x8 s;
#pragma unroll
                for (int j = 0; j < 8; j++) s[j] = (short)bf16rne(bf16tof(u[j]) * 0.18033688f);
                qf[db] = s;
            }
        }

        f32x4 O[4] = {};                 // O^T: O[dt] reg r = O[q=lr][d = 16dt + 4lg + r]
        float m_i = -1e30f, l_i = 0.0f;  // for q-row (qrow0 + lr)

        // prologue: stage kv tile 0 into buf 0 (prev phase's trailing barrier protects LDS)
        {
            u16x8 k0v = *(const u16x8*)(Kbase + (size_t)srow * NQKV_ + scol);
            u16x8 v0v = *(const u16x8*)(Vbase + (size_t)srow * S_ + scol);
            *(u16x8*)&Ks[0][srow][scol] = k0v;
            *(u16x8*)&Vs[0][srow][scol] = v0v;
        }
        __syncthreads();

        int cb = 0;
        for (int t = 0; t < nt; t++) {
            int kv0 = t * 64;
            bool notlast = (t + 1 < nt);
            // T14: issue next tile's global loads early (hide HBM/L2 under compute)
            u16x8 kn, vn;
            if (notlast) {
                kn = *(const u16x8*)(Kbase + (size_t)(kv0 + 64 + srow) * NQKV_ + scol);
                vn = *(const u16x8*)(Vbase + (size_t)srow * S_ + kv0 + 64 + scol);
            }

            // swapped QK^T: Sc[t4][r] = S[kv0+16t4+4lg+r][qrow0+lr]
            f32x4 Sc[4] = {};
            __builtin_amdgcn_s_setprio(1);
#pragma unroll
            for (int t4 = 0; t4 < 4; t4++) {
#pragma unroll
                for (int db = 0; db < 2; db++) {
                    s16x8 kf = *(const s16x8*)&Ks[cb][t4 * 16 + lr][db * 32 + lg * 8];
                    Sc[t4] = __builtin_amdgcn_mfma_f32_16x16x32_bf16(kf, qf[db], Sc[t4], 0, 0, 0);
                }
            }
            __builtin_amdgcn_s_setprio(0);
            // causal mask: only last tile is partial (block-uniform branch)
            if (t == nt - 1) {
                int qr = qrow0 + lr;
#pragma unroll
                for (int t4 = 0; t4 < 4; t4++)
#pragma unroll
                    for (int r = 0; r < 4; r++) {
                        int kvi = kv0 + t4 * 16 + lg * 4 + r;
                        Sc[t4][r] = (kvi <= qr) ? Sc[t4][r] : -1e30f;
                    }
            }
            // lane-local softmax for q-row (qrow0+lr); row spread over lanes {lr,+16,+32,+48}
            f32x4 mm = vmax4(vmax4(Sc[0], Sc[1]), vmax4(Sc[2], Sc[3]));
            float mx = fmaxf(fmaxf(mm[0], mm[1]), fmaxf(mm[2], mm[3]));
            mx = fmaxf(mx, __shfl_xor(mx, 16));
            mx = fmaxf(mx, __shfl_xor(mx, 32));
            float newm = fmaxf(m_i, mx);
            float alpha = exp2f(m_i - newm);
            m_i = newm;
            f32x4 p4[4];
#pragma unroll
            for (int t4 = 0; t4 < 4; t4++)
#pragma unroll
                for (int r = 0; r < 4; r++)
                    p4[t4][r] = exp2f(Sc[t4][r] - newm);
            f32x4 ss = (p4[0] + p4[1]) + (p4[2] + p4[3]);
            float rs = (ss[0] + ss[1]) + (ss[2] + ss[3]);
            rs += __shfl_xor(rs, 16);
            rs += __shfl_xor(rs, 32);
            l_i = l_i * alpha + rs;
            // O rescale: alpha belongs to q=lr == this lane's O rows (lane-local)
#pragma unroll
            for (int dt = 0; dt < 4; dt++)
#pragma unroll
                for (int r = 0; r < 4; r++) O[dt][r] *= alpha;
            // pack P to bf16 B-fragments in-register (RNE; cvt_pk truncates -> bias, rounds 6/8)
            s16x4 pa[4];
#pragma unroll
            for (int t4 = 0; t4 < 4; t4++) {
                u16x4 w;
#pragma unroll
                for (int r = 0; r < 4; r++) w[r] = bf16rne(p4[t4][r]);
                union { u16x4 u; s16x4 s; } uu; uu.u = w;
                pa[t4] = uu.s;
            }
            // PV transposed: O^T += V^T * P; A-frag = Vs rows (8B LDS reads), B-frag = pa
            __builtin_amdgcn_s_setprio(1);
#pragma unroll
            for (int t4 = 0; t4 < 4; t4++) {
#pragma unroll
                for (int dt = 0; dt < 4; dt++) {
                    s16x4 va = *(const s16x4*)&Vs[cb][dt * 16 + lr][t4 * 16 + lg * 4];
                    O[dt] = mfma16x16x16_bf16(va, pa[t4], O[dt]);
                }
            }
            __builtin_amdgcn_s_setprio(0);
            // write staged regs to the other buffer (nobody reads it this iter)
            if (notlast) {
                *(u16x8*)&Ks[cb ^ 1][srow][scol] = kn;
                *(u16x8*)&Vs[cb ^ 1][srow][scol] = vn;
            }
            __syncthreads();         // single barrier: staging visible + reads done
            cb ^= 1;
        }

        // epilogue: lane-local 1/l; lane writes q-row (qrow0+lr), 4 contiguous d per dt
        float il = 1.0f / l_i;
        u16* orow = attn_out + (size_t)(b * S_ + qrow0 + lr) * HID_ + h * 64 + lg * 4;
#pragma unroll
        for (int dt = 0; dt < 4; dt++) {
            u16x4 w;
#pragma unroll
            for (int r = 0; r < 4; r++) w[r] = bf16rne(O[dt][r] * il);
            *(u16x4*)(orow + dt * 16) = w;
        }
    }
}

extern "C" void kernel_launch(void* const* d_in, const int* in_sizes, int n_in,
                              void* d_out, int out_size, void* d_ws, size_t ws_size,
                              hipStream_t stream) {
    const float* x  = (const float*)d_in[0];
    // d_in[1] = mask (causal, implemented structurally)
    const float* Wq = (const float*)d_in[2];
    const float* bq = (const float*)d_in[3];
    const float* Wk = (const float*)d_in[4];
    const float* bk = (const float*)d_in[5];
    const float* Wv = (const float*)d_in[6];
    const float* bv = (const float*)d_in[7];
    const float* Wo = (const float*)d_in[8];
    const float* bo = (const float*)d_in[9];
    float* out = (float*)d_out;

    char* ws = (char*)d_ws;
    u16* xb     = (u16*)(ws);                              // 16.78 MB
    u16* wqkvT  = (u16*)(ws + 16777216);                   // 12.58 MB
    u16* woT    = (u16*)(ws + 29360128);                   // 8.39 MB
    u16* qkv    = (u16*)(ws + 37748736);                   // 25.17 MB
    u16* vT     = (u16*)(ws + 62914560);                   // 4.19 MB
    u16* attnO  = (u16*)(ws + 67108864);                   // 16.78 MB
    float* biasQ = (float*)(ws + 83886080);                // 12 KB

    // 1. convert x to bf16
    {
        int n4 = (M_ * HID_) / 4;  // 2097152
        convert_x_kernel<<<(n4 + 255) / 256, 256, 0, stream>>>(x, xb, n4);
    }
    // 2. pack qkv bias
    pack_bias_kernel<<<(NQKV_ + 255) / 256, 256, 0, stream>>>(bq, bk, bv, biasQ);
    // 3. transpose weights
    {
        dim3 blk(32, 8);
        transpose_w_kernel<<<dim3(64, 64), blk, 0, stream>>>(Wq, 2048, wqkvT);
        transpose_w_kernel<<<dim3(16, 64), blk, 0, stream>>>(Wk, 512, wqkvT + (size_t)2048 * 2048);
        transpose_w_kernel<<<dim3(16, 64), blk, 0, stream>>>(Wv, 512, wqkvT + (size_t)2560 * 2048);
        transpose_w_kernel<<<dim3(64, 64), blk, 0, stream>>>(Wo, 2048, woT);
    }
    // 4. QKV GEMM: [4096,3072] = xb @ wqkvT^T + biasQ  (bf16 out)
    gemm_bt_kernel<true><<<dim3(NQKV_ / 128, M_ / 128), 256, 0, stream>>>(
        xb, wqkvT, biasQ, qkv, M_, NQKV_, HID_);
    // 5. transpose V
    transpose_v_kernel<<<dim3(64, 2, 16), dim3(32, 8), 0, stream>>>(qkv, vT);
    // 6. attention: 512 blocks, 8 waves / 4 heads share staged K/V, paired causal q-tiles
    attn_kernel<<<dim3(32, B_ * NKV_), 512, 0, stream>>>(qkv, vT, attnO);
    // 7. output GEMM: [4096,2048] = attnO @ woT^T + bo  (fp32 out)
    gemm_bt_kernel<false><<<dim3(HID_ / 128, M_ / 128), 256, 0, stream>>>(
        attnO, woT, bo, out, M_, HID_, HID_);
}

// Round 13
// 222.994 us; speedup vs baseline: 1.2943x; 1.0230x over previous
//
#include <hip/hip_runtime.h>

typedef unsigned short u16;
typedef __attribute__((ext_vector_type(8))) short s16x8;
typedef __attribute__((ext_vector_type(4))) short s16x4;
typedef __attribute__((ext_vector_type(8))) unsigned short u16x8;
typedef __attribute__((ext_vector_type(4))) unsigned short u16x4;
typedef __attribute__((ext_vector_type(4))) float f32x4;

#define B_ 2
#define S_ 2048
#define HID_ 2048
#define NH_ 32
#define NKV_ 8
#define HD_ 64
#define M_ (B_ * S_)          // 4096
#define NQKV_ 3072            // 2048 q + 512 k + 512 v

__device__ __forceinline__ u16 bf16rne(float f) {
    union { float f; unsigned u; } x; x.f = f;
    unsigned u = x.u;
    u += 0x7fffu + ((u >> 16) & 1u);
    return (u16)(u >> 16);
}
__device__ __forceinline__ float bf16tof(u16 h) {
    union { unsigned u; float f; } x; x.u = ((unsigned)h) << 16;
    return x.f;
}
__device__ __forceinline__ f32x4 vmax4(f32x4 a, f32x4 b) {
    f32x4 r;
    r[0] = fmaxf(a[0], b[0]); r[1] = fmaxf(a[1], b[1]);
    r[2] = fmaxf(a[2], b[2]); r[3] = fmaxf(a[3], b[3]);
    return r;
}
__device__ __forceinline__ f32x4 mfma16x16x16_bf16(s16x4 a, s16x4 b, f32x4 c) {
#if __has_builtin(__builtin_amdgcn_mfma_f32_16x16x16bf16_1k)
    return __builtin_amdgcn_mfma_f32_16x16x16bf16_1k(a, b, c, 0, 0, 0);
#else
    f32x4 d = c;
    asm volatile("v_mfma_f32_16x16x16_bf16 %0, %1, %2, %0" : "+v"(d) : "v"(a), "v"(b));
    return d;
#endif
}

// async global->LDS, 16B per lane; LDS dest = wave-uniform base + lane*16
__device__ __forceinline__ void gload16(const void* g, void* l) {
    __builtin_amdgcn_global_load_lds(
        (const __attribute__((address_space(1))) unsigned int*)g,
        (__attribute__((address_space(3))) unsigned int*)l, 16, 0, 0);
}

// ---------------- fp32 -> bf16 convert (x) ----------------
__global__ __launch_bounds__(256) void convert_x_kernel(const float* __restrict__ src,
                                                        u16* __restrict__ dst, int n4) {
    int i = blockIdx.x * 256 + threadIdx.x;
    if (i >= n4) return;
    f32x4 v = *(const f32x4*)(src + (size_t)i * 4);
    u16x4 o;
    o[0] = bf16rne(v[0]); o[1] = bf16rne(v[1]); o[2] = bf16rne(v[2]); o[3] = bf16rne(v[3]);
    *(u16x4*)(dst + (size_t)i * 4) = o;
}

// ---------------- pack qkv bias (fp32) ----------------
__global__ void pack_bias_kernel(const float* bq, const float* bk, const float* bv,
                                 float* __restrict__ dst) {
    int i = blockIdx.x * 256 + threadIdx.x;
    if (i >= NQKV_) return;
    float v;
    if (i < 2048) v = bq[i];
    else if (i < 2560) v = bk[i - 2048];
    else v = bv[i - 2560];
    dst[i] = v;
}

// ---------------- all weight transposes in ONE dispatch ----------------
// z=0: Wq [2048][2048] -> wqkvT rows 0..2047       z=1: Wk [2048][512] -> rows 2048..2559
// z=2: Wv [2048][512]  -> rows 2560..3071          z=3: Wo [2048][2048] -> woT
__global__ __launch_bounds__(256) void transpose_w_all_kernel(
    const float* __restrict__ Wq, const float* __restrict__ Wk,
    const float* __restrict__ Wv, const float* __restrict__ Wo,
    u16* __restrict__ wqkvT, u16* __restrict__ woT) {
    __shared__ float tile[32][33];
    int z = blockIdx.z;
    const float* src; u16* dst; int N;
    if (z == 0)      { src = Wq; dst = wqkvT;                          N = 2048; }
    else if (z == 1) { src = Wk; dst = wqkvT + (size_t)2048 * 2048;    N = 512;  }
    else if (z == 2) { src = Wv; dst = wqkvT + (size_t)2560 * 2048;    N = 512;  }
    else             { src = Wo; dst = woT;                            N = 2048; }
    int n0 = blockIdx.x * 32;
    if (n0 >= N) return;           // Wk/Wv use only 16 of 64 x-blocks
    int k0 = blockIdx.y * 32;
    int tx = threadIdx.x;   // 0..31
    int ty = threadIdx.y;   // 0..7
    for (int i = 0; i < 32; i += 8)
        tile[ty + i][tx] = src[(size_t)(k0 + ty + i) * N + n0 + tx];
    __syncthreads();
    for (int i = 0; i < 32; i += 8)
        dst[(size_t)(n0 + ty + i) * 2048 + k0 + tx] = bf16rne(tile[tx][ty + i]);
}

// ---------------- bf16 GEMM (m97 structure + T1 XCD swizzle) ----------------
// C[M][N] = A[M][K]*Bt[N][K]^T + bias; 128x128 tile, BK=64, 4 waves 2x2.
// FUSE_VT: for cols >= 2560 (the V slice of the QKV GEMM), write the transposed
// copy vT[(b*8+kv)*64+d][s] directly (aligned u16x4 over 4 consecutive s) and skip
// the qkv store (nothing reads qkv's V region afterwards).
template <bool OUT_BF16, bool FUSE_VT>
__global__ __launch_bounds__(256) void gemm_bt_kernel(const u16* __restrict__ A,
                                                      const u16* __restrict__ Bt,
                                                      const float* __restrict__ bias,
                                                      void* __restrict__ Cout,
                                                      u16* __restrict__ vTp,
                                                      int M, int N, int K) {
    __shared__ u16 As[128][64];
    __shared__ u16 Bs[128][64];
    // T1: XCD-aware block swizzle (requires nwg % 8 == 0 -- true for 768 and 512)
    int nwg = (int)(gridDim.x * gridDim.y);
    int bid = (int)(blockIdx.y * gridDim.x + blockIdx.x);
    int swz = (bid & 7) * (nwg >> 3) + (bid >> 3);
    int bn = (swz % (int)gridDim.x) * 128;
    int bm = (swz / (int)gridDim.x) * 128;
    int tid = threadIdx.x;
    int lane = tid & 63, wid = tid >> 6;
    int wr = wid >> 1, wc = wid & 1;
    int lr = lane & 15, lg = lane >> 4;
    f32x4 acc[4][4] = {};

    int srow_l = lane >> 3;                 // 0..7
    int schunk = (lane & 7) ^ srow_l;       // source chunk for linear LDS dest (XOR swizzle)
    int scol = schunk * 8;                  // element offset in K

    for (int k0 = 0; k0 < K; k0 += 64) {
        __syncthreads();   // previous compute done before overwrite
#pragma unroll
        for (int c = 0; c < 4; c++) {
            int row = c * 32 + wid * 8;
            gload16(A + (size_t)(bm + row + srow_l) * K + k0 + scol, &As[row][0]);
            gload16(Bt + (size_t)(bn + row + srow_l) * K + k0 + scol, &Bs[row][0]);
        }
        asm volatile("s_waitcnt vmcnt(0)" ::: "memory");
        __syncthreads();   // all waves' loads landed
#pragma unroll
        for (int kk = 0; kk < 2; kk++) {
            s16x8 a[4], b[4];
#pragma unroll
            for (int mi = 0; mi < 4; mi++) {
                int row = wr * 64 + mi * 16 + lr;
                int cc = ((kk << 2) + lg) ^ (lr & 7);
                a[mi] = *(const s16x8*)&As[row][cc << 3];
            }
#pragma unroll
            for (int ni = 0; ni < 4; ni++) {
                int row = wc * 64 + ni * 16 + lr;
                int cc = ((kk << 2) + lg) ^ (lr & 7);
                b[ni] = *(const s16x8*)&Bs[row][cc << 3];
            }
#pragma unroll
            for (int mi = 0; mi < 4; mi++)
#pragma unroll
                for (int ni = 0; ni < 4; ni++)
                    acc[mi][ni] = __builtin_amdgcn_mfma_f32_16x16x32_bf16(a[mi], b[ni], acc[mi][ni], 0, 0, 0);
        }
    }

#pragma unroll
    for (int mi = 0; mi < 4; mi++)
#pragma unroll
        for (int ni = 0; ni < 4; ni++) {
            int col = bn + wc * 64 + ni * 16 + lr;
            float bsv = bias ? bias[col] : 0.0f;
            int row0 = bm + wr * 64 + mi * 16 + lg * 4;
            if (FUSE_VT && col >= 2560) {
                // V slice: write transposed copy only. 4 consecutive rows share b
                // (128-tiles never straddle the 2048 batch boundary).
                int kvd = col - 2560;          // kv*64 + d
                int bq_ = row0 >> 11;          // batch index
                int s0 = row0 & 2047;
                u16x4 w;
#pragma unroll
                for (int r = 0; r < 4; r++) w[r] = bf16rne(acc[mi][ni][r] + bsv);
                *(u16x4*)(vTp + (size_t)(bq_ * 8 * 64 + kvd) * 2048 + s0) = w;
            } else {
#pragma unroll
                for (int r = 0; r < 4; r++) {
                    float v = acc[mi][ni][r] + bsv;
                    if (OUT_BF16)
                        ((u16*)Cout)[(size_t)(row0 + r) * N + col] = bf16rne(v);
                    else
                        ((float*)Cout)[(size_t)(row0 + r) * N + col] = v;
                }
            }
        }
}

// ---------------- flash attention (r10 config): 8 waves / 4 q-heads share staged K/V; ----------
// paired causal q-tiles {bx, 63-bx} -> every block does ~33-34 kv-tile visits (zero tail).
// Q prescaled by 0.125*log2(e); softmax exp2-domain, always-rescale (P<=1), RNE pack.
// Swapped QK^T: lane (lr,lg) reg r = S[kv=16t4+4lg+r][q=lr].
// Transposed PV: O^T = V^T*P (16x16x16); alpha/l lane-local; contiguous 8B epilogue stores.
__global__ __launch_bounds__(512) void attn_kernel(const u16* __restrict__ qkv,
                                                   const u16* __restrict__ vT,
                                                   u16* __restrict__ attn_out) {
    int bx = blockIdx.x;             // 0..31
    int bkv = blockIdx.y;            // 0..15
    int b = bkv >> 3, kvh = bkv & 7;
    int tid = threadIdx.x;
    int lane = tid & 63, wid = tid >> 6;   // 8 waves
    int lr = lane & 15, lg = lane >> 4;
    int h = kvh * 4 + (wid >> 1);    // q head: 2 waves per head
    int sub = wid & 1;               // 16-row subtile within the 32-row q-tile

    __shared__ u16 Ks[2][64][72];    // [buf][kv][d] padded (144B stride)
    __shared__ u16 Vs[2][64][72];    // [buf][d][kv] padded

    const u16* Kbase = qkv + (size_t)(b * S_) * NQKV_ + 2048 + kvh * 64;  // + s*NQKV_
    const u16* Vbase = vT + (size_t)(b * 8 + kvh) * 64 * S_;              // + d*S_

    int srow = tid >> 3;             // 0..63 (one staging pass, 512 threads)
    int scol = (tid & 7) * 8;

#pragma unroll 1
    for (int phase = 0; phase < 2; phase++) {
        int qt = phase ? (63 - bx) : bx;   // 32-row q-tile index
        int qrow0 = qt * 32 + sub * 16;    // this wave's first q row
        int nt = qt / 2 + 1;               // kv tiles of 64 covering causal extent

        // Q as B-fragment: lane holds Q[q=lr][d = db*32 + lg*8 + j], prescaled
        s16x8 qf[2];
        {
            const u16* qr = qkv + (size_t)(b * S_ + qrow0 + lr) * NQKV_ + h * 64;
#pragma unroll
            for (int db = 0; db < 2; db++) {
                u16x8 u = *(const u16x8*)(qr + db * 32 + lg * 8);
                s16x8 s;
#pragma unroll
                for (int j = 0; j < 8; j++) s[j] = (short)bf16rne(bf16tof(u[j]) * 0.18033688f);
                qf[db] = s;
            }
        }

        f32x4 O[4] = {};                 // O^T: O[dt] reg r = O[q=lr][d = 16dt + 4lg + r]
        float m_i = -1e30f, l_i = 0.0f;  // for q-row (qrow0 + lr)

        // prologue: stage kv tile 0 into buf 0 (prev phase's trailing barrier protects LDS)
        {
            u16x8 k0v = *(const u16x8*)(Kbase + (size_t)srow * NQKV_ + scol);
            u16x8 v0v = *(const u16x8*)(Vbase + (size_t)srow * S_ + scol);
            *(u16x8*)&Ks[0][srow][scol] = k0v;
            *(u16x8*)&Vs[0][srow][scol] = v0v;
        }
        __syncthreads();

        int cb = 0;
        for (int t = 0; t < nt; t++) {
            int kv0 = t * 64;
            bool notlast = (t + 1 < nt);
            // T14: issue next tile's global loads early (hide HBM/L2 under compute)
            u16x8 kn, vn;
            if (notlast) {
                kn = *(const u16x8*)(Kbase + (size_t)(kv0 + 64 + srow) * NQKV_ + scol);
                vn = *(const u16x8*)(Vbase + (size_t)srow * S_ + kv0 + 64 + scol);
            }

            // swapped QK^T: Sc[t4][r] = S[kv0+16t4+4lg+r][qrow0+lr]
            f32x4 Sc[4] = {};
            __builtin_amdgcn_s_setprio(1);
#pragma unroll
            for (int t4 = 0; t4 < 4; t4++) {
#pragma unroll
                for (int db = 0; db < 2; db++) {
                    s16x8 kf = *(const s16x8*)&Ks[cb][t4 * 16 + lr][db * 32 + lg * 8];
                    Sc[t4] = __builtin_amdgcn_mfma_f32_16x16x32_bf16(kf, qf[db], Sc[t4], 0, 0, 0);
                }
            }
            __builtin_amdgcn_s_setprio(0);
            // causal mask: only last tile is partial (block-uniform branch)
            if (t == nt - 1) {
                int qr = qrow0 + lr;
#pragma unroll
                for (int t4 = 0; t4 < 4; t4++)
#pragma unroll
                    for (int r = 0; r < 4; r++) {
                        int kvi = kv0 + t4 * 16 + lg * 4 + r;
                        Sc[t4][r] = (kvi <= qr) ? Sc[t4][r] : -1e30f;
                    }
            }
            // lane-local softmax for q-row (qrow0+lr); row spread over lanes {lr,+16,+32,+48}
            f32x4 mm = vmax4(vmax4(Sc[0], Sc[1]), vmax4(Sc[2], Sc[3]));
            float mx = fmaxf(fmaxf(mm[0], mm[1]), fmaxf(mm[2], mm[3]));
            mx = fmaxf(mx, __shfl_xor(mx, 16));
            mx = fmaxf(mx, __shfl_xor(mx, 32));
            float newm = fmaxf(m_i, mx);
            float alpha = exp2f(m_i - newm);
            m_i = newm;
            f32x4 p4[4];
#pragma unroll
            for (int t4 = 0; t4 < 4; t4++)
#pragma unroll
                for (int r = 0; r < 4; r++)
                    p4[t4][r] = exp2f(Sc[t4][r] - newm);
            f32x4 ss = (p4[0] + p4[1]) + (p4[2] + p4[3]);
            float rs = (ss[0] + ss[1]) + (ss[2] + ss[3]);
            rs += __shfl_xor(rs, 16);
            rs += __shfl_xor(rs, 32);
            l_i = l_i * alpha + rs;
            // O rescale: alpha belongs to q=lr == this lane's O rows (lane-local)
#pragma unroll
            for (int dt = 0; dt < 4; dt++)
#pragma unroll
                for (int r = 0; r < 4; r++) O[dt][r] *= alpha;
            // pack P to bf16 B-fragments in-register (RNE; cvt_pk truncates -> bias, rounds 6/8)
            s16x4 pa[4];
#pragma unroll
            for (int t4 = 0; t4 < 4; t4++) {
                u16x4 w;
#pragma unroll
                for (int r = 0; r < 4; r++) w[r] = bf16rne(p4[t4][r]);
                union { u16x4 u; s16x4 s; } uu; uu.u = w;
                pa[t4] = uu.s;
            }
            // PV transposed: O^T += V^T * P; A-frag = Vs rows (8B LDS reads), B-frag = pa
            __builtin_amdgcn_s_setprio(1);
#pragma unroll
            for (int t4 = 0; t4 < 4; t4++) {
#pragma unroll
                for (int dt = 0; dt < 4; dt++) {
                    s16x4 va = *(const s16x4*)&Vs[cb][dt * 16 + lr][t4 * 16 + lg * 4];
                    O[dt] = mfma16x16x16_bf16(va, pa[t4], O[dt]);
                }
            }
            __builtin_amdgcn_s_setprio(0);
            // write staged regs to the other buffer (nobody reads it this iter)
            if (notlast) {
                *(u16x8*)&Ks[cb ^ 1][srow][scol] = kn;
                *(u16x8*)&Vs[cb ^ 1][srow][scol] = vn;
            }
            __syncthreads();         // single barrier: staging visible + reads done
            cb ^= 1;
        }

        // epilogue: lane-local 1/l; lane writes q-row (qrow0+lr), 4 contiguous d per dt
        float il = 1.0f / l_i;
        u16* orow = attn_out + (size_t)(b * S_ + qrow0 + lr) * HID_ + h * 64 + lg * 4;
#pragma unroll
        for (int dt = 0; dt < 4; dt++) {
            u16x4 w;
#pragma unroll
            for (int r = 0; r < 4; r++) w[r] = bf16rne(O[dt][r] * il);
            *(u16x4*)(orow + dt * 16) = w;
        }
    }
}

extern "C" void kernel_launch(void* const* d_in, const int* in_sizes, int n_in,
                              void* d_out, int out_size, void* d_ws, size_t ws_size,
                              hipStream_t stream) {
    const float* x  = (const float*)d_in[0];
    // d_in[1] = mask (causal, implemented structurally)
    const float* Wq = (const float*)d_in[2];
    const float* bq = (const float*)d_in[3];
    const float* Wk = (const float*)d_in[4];
    const float* bk = (const float*)d_in[5];
    const float* Wv = (const float*)d_in[6];
    const float* bv = (const float*)d_in[7];
    const float* Wo = (const float*)d_in[8];
    const float* bo = (const float*)d_in[9];
    float* out = (float*)d_out;

    char* ws = (char*)d_ws;
    u16* xb     = (u16*)(ws);                              // 16.78 MB
    u16* wqkvT  = (u16*)(ws + 16777216);                   // 12.58 MB
    u16* woT    = (u16*)(ws + 29360128);                   // 8.39 MB
    u16* qkv    = (u16*)(ws + 37748736);                   // 25.17 MB
    u16* vT     = (u16*)(ws + 62914560);                   // 4.19 MB
    u16* attnO  = (u16*)(ws + 67108864);                   // 16.78 MB
    float* biasQ = (float*)(ws + 83886080);                // 12 KB

    // 1. convert x to bf16
    {
        int n4 = (M_ * HID_) / 4;  // 2097152
        convert_x_kernel<<<(n4 + 255) / 256, 256, 0, stream>>>(x, xb, n4);
    }
    // 2. pack qkv bias
    pack_bias_kernel<<<(NQKV_ + 255) / 256, 256, 0, stream>>>(bq, bk, bv, biasQ);
    // 3. all weight transposes in one dispatch
    transpose_w_all_kernel<<<dim3(64, 64, 4), dim3(32, 8), 0, stream>>>(
        Wq, Wk, Wv, Wo, wqkvT, woT);
    // 4. QKV GEMM: [4096,3072] = xb @ wqkvT^T + biasQ  (bf16 out; V slice -> vT directly)
    gemm_bt_kernel<true, true><<<dim3(NQKV_ / 128, M_ / 128), 256, 0, stream>>>(
        xb, wqkvT, biasQ, qkv, vT, M_, NQKV_, HID_);
    // 5. attention: 512 blocks, 8 waves / 4 heads share staged K/V, paired causal q-tiles
    attn_kernel<<<dim3(32, B_ * NKV_), 512, 0, stream>>>(qkv, vT, attnO);
    // 6. output GEMM: [4096,2048] = attnO @ woT^T + bo  (fp32 out)
    gemm_bt_kernel<false, false><<<dim3(HID_ / 128, M_ / 128), 256, 0, stream>>>(
        attnO, woT, bo, out, nullptr, M_, HID_, HID_);
}